// Round 1
// baseline (40.882 us; speedup 1.0000x reference)
//
#include <hip/hip_runtime.h>

// Problem constants (from setup_inputs): b=4, f=6, n_slots=7, n_buffer=8,
// h=w=128, 3 channels. bf = 24.
constexpr int NB  = 8;            // n_buffer
constexpr int NS  = 7;            // n_slots
constexpr int NCH = 3;
constexpr int HW  = 128 * 128;    // 16384
constexpr int HW4 = HW / 4;
constexpr int BF  = 24;           // b*f
constexpr int CHUNKS = 64;        // chunks per bf; 64 thr * 4 px = 256 px/chunk
constexpr float INV_HW = 1.0f / (float)HW;
constexpr float SCALE  = 20.0f / (4.0f * 6.0f * 7.0f * 8.0f);  // LOSS_WEIGHT / (b*f*ns*nb)
constexpr float LOG_CLAMP = -100.0f;

__global__ __launch_bounds__(64)
void em_loss_kernel(const float* __restrict__ seg,
                    const float* __restrict__ masks,
                    const float* __restrict__ rec,
                    const float* __restrict__ rtgt,
                    const float* __restrict__ mvis,
                    const float* __restrict__ ai,
                    float* __restrict__ out) {
    const int bf    = blockIdx.x >> 6;          // /CHUNKS
    const int chunk = blockIdx.x & (CHUNKS - 1);
    const int hw0   = (chunk << 8) + ((int)threadIdx.x << 2);  // 4 consecutive px

    // ai[bf] (7x8) into LDS; column sums A[c] = sum_s ai[s,c].
    __shared__ float ai_s[NS][NB];
    __shared__ float A_s[NB];
    if (threadIdx.x < NS * NB)
        ((float*)ai_s)[threadIdx.x] = ai[bf * NS * NB + (int)threadIdx.x];
    __syncthreads();
    if (threadIdx.x < NB) {
        float a = 0.f;
        #pragma unroll
        for (int s = 0; s < NS; ++s) a += ai_s[s][threadIdx.x];
        A_s[threadIdx.x] = a;
    }
    __syncthreads();

    const float4* segp = (const float4*)(seg  + (size_t)bf * NB * HW)        + (hw0 >> 2);
    const float4* mp   = (const float4*)(masks + (size_t)bf * NS * HW)       + (hw0 >> 2);
    const float4* rp   = (const float4*)(rec  + (size_t)bf * NB * NCH * HW)  + (hw0 >> 2);
    const float4* tp   = (const float4*)(rtgt + (size_t)bf * NCH * HW)       + (hw0 >> 2);
    const float4* vp   = (const float4*)(mvis + (size_t)bf * NS * HW)        + (hw0 >> 2);

    // rec_tgt: 3 channels x 4 px
    float t[NCH][4];
    #pragma unroll
    for (int ch = 0; ch < NCH; ++ch) {
        float4 v = tp[ch * HW4];
        t[ch][0] = v.x; t[ch][1] = v.y; t[ch][2] = v.z; t[ch][3] = v.w;
    }

    // mask bits: 7 slots x 4 px, both mask tensors
    float m[NS][4], vv[NS][4];
    #pragma unroll
    for (int s = 0; s < NS; ++s) {
        float4 a = mp[s * HW4];
        m[s][0] = a.x; m[s][1] = a.y; m[s][2] = a.z; m[s][3] = a.w;
        float4 b = vp[s * HW4];
        vv[s][0] = b.x; vv[s][1] = b.y; vv[s][2] = b.z; vv[s][3] = b.w;
    }

    float acc = 0.f;
    #pragma unroll
    for (int c = 0; c < NB; ++c) {
        float4 s4 = segp[c * HW4];
        float sv[4] = { s4.x, s4.y, s4.z, s4.w };
        float4 r0 = rp[(c * NCH + 0) * HW4];
        float4 r1 = rp[(c * NCH + 1) * HW4];
        float4 r2 = rp[(c * NCH + 2) * HW4];
        float rr[NCH][4] = {
            { r0.x, r0.y, r0.z, r0.w },
            { r1.x, r1.y, r1.z, r1.w },
            { r2.x, r2.y, r2.z, r2.w },
        };
        const float Ac = A_s[c];
        #pragma unroll
        for (int j = 0; j < 4; ++j) {
            float s  = sv[j];
            float lp = fmaxf(__logf(s), LOG_CLAMP);
            float l1 = fmaxf(__logf(1.0f - s), LOG_CLAMP);
            float d0 = rr[0][j] - t[0][j];
            float d1 = rr[1][j] - t[1][j];
            float d2 = rr[2][j] - t[2][j];
            float D  = d0 * d0 + d1 * d1 + d2 * d2;
            float U = 0.f, V = 0.f;
            #pragma unroll
            for (int s7 = 0; s7 < NS; ++s7) {
                float a = ai_s[s7][c];
                U += (m[s7][j]  > 0.5f) ? a : 0.f;
                V += (vv[s7][j] > 0.5f) ? a : 0.f;
            }
            acc += -(Ac * l1 + U * (lp - l1)) * INV_HW + 0.1f * V * D;
        }
    }

    // wave (=block) reduction, one atomic per block
    #pragma unroll
    for (int off = 32; off; off >>= 1) acc += __shfl_down(acc, off, 64);
    if (threadIdx.x == 0) atomicAdd(out, acc * SCALE);
}

extern "C" void kernel_launch(void* const* d_in, const int* in_sizes, int n_in,
                              void* d_out, int out_size, void* d_ws, size_t ws_size,
                              hipStream_t stream) {
    const float* seg   = (const float*)d_in[0];  // (4,6,8,128,128)
    const float* masks = (const float*)d_in[1];  // (4,6,7,128,128)
    const float* rec   = (const float*)d_in[2];  // (4,6,8,3,128,128)
    const float* rtgt  = (const float*)d_in[3];  // (4,6,3,128,128)
    const float* mvis  = (const float*)d_in[4];  // (4,6,7,128,128)
    const float* ai    = (const float*)d_in[5];  // (4,6,7,8)
    float* out = (float*)d_out;

    hipMemsetAsync(out, 0, sizeof(float), stream);
    em_loss_kernel<<<BF * CHUNKS, 64, 0, stream>>>(seg, masks, rec, rtgt, mvis, ai, out);
}

// Round 2
// 30.923 us; speedup vs baseline: 1.3221x; 1.3221x over previous
//
#include <hip/hip_runtime.h>

// Problem constants: b=4, f=6, n_slots=7, n_buffer=8, h=w=128, 3 channels.
constexpr int NB  = 8;
constexpr int NS  = 7;
constexpr int NCH = 3;
constexpr int HW  = 128 * 128;    // 16384
constexpr int HW2 = HW / 2;       // float2 stride between channel planes
constexpr int BF  = 24;
constexpr int BLOCK = 256;
constexpr int PX_PER_BLOCK = BLOCK * 2;          // 512
constexpr int CHUNKS = HW / PX_PER_BLOCK;        // 32 blocks per bf
constexpr float INV_HW = 1.0f / (float)HW;
constexpr float SCALE  = 20.0f / (4.0f * 6.0f * 7.0f * 8.0f);
constexpr float LOG_CLAMP = -100.0f;

__global__ __launch_bounds__(BLOCK)
void em_loss_kernel(const float* __restrict__ seg,
                    const float* __restrict__ masks,
                    const float* __restrict__ rec,
                    const float* __restrict__ rtgt,
                    const float* __restrict__ mvis,
                    const float* __restrict__ ai,
                    float* __restrict__ out) {
    const int bf    = blockIdx.x >> 5;           // / CHUNKS
    const int chunk = blockIdx.x & (CHUNKS - 1);
    const int tid   = threadIdx.x;
    const int hw0   = chunk * PX_PER_BLOCK + tid * 2;   // 2 consecutive px

    __shared__ float ai_s[NS][NB];
    __shared__ float A_s[NB];
    if (tid < NS * NB)
        ((float*)ai_s)[tid] = ai[bf * NS * NB + tid];
    __syncthreads();
    if (tid < NB) {
        float a = 0.f;
        #pragma unroll
        for (int s = 0; s < NS; ++s) a += ai_s[s][tid];
        A_s[tid] = a;
    }
    __syncthreads();

    const float2* segp = (const float2*)(seg  + (size_t)bf * NB * HW)       + (hw0 >> 1);
    const float2* mp   = (const float2*)(masks + (size_t)bf * NS * HW)      + (hw0 >> 1);
    const float2* rp   = (const float2*)(rec  + (size_t)bf * NB * NCH * HW) + (hw0 >> 1);
    const float2* tp   = (const float2*)(rtgt + (size_t)bf * NCH * HW)      + (hw0 >> 1);
    const float2* vp   = (const float2*)(mvis + (size_t)bf * NS * HW)       + (hw0 >> 1);

    // rec_tgt: 3 channels x 2 px
    float t[NCH][2];
    #pragma unroll
    for (int ch = 0; ch < NCH; ++ch) {
        float2 v = tp[ch * HW2];
        t[ch][0] = v.x; t[ch][1] = v.y;
    }

    // mask bits as 0/1 floats (c-independent, computed once)
    float mb[2][NS], vb[2][NS];
    #pragma unroll
    for (int s = 0; s < NS; ++s) {
        float2 a = mp[s * HW2];
        mb[0][s] = (a.x > 0.5f) ? 1.f : 0.f;
        mb[1][s] = (a.y > 0.5f) ? 1.f : 0.f;
        float2 b = vp[s * HW2];
        vb[0][s] = (b.x > 0.5f) ? 1.f : 0.f;
        vb[1][s] = (b.y > 0.5f) ? 1.f : 0.f;
    }

    float acc = 0.f;
    #pragma unroll
    for (int c = 0; c < NB; ++c) {
        float2 s2 = segp[c * HW2];
        float2 r0 = rp[(c * NCH + 0) * HW2];
        float2 r1 = rp[(c * NCH + 1) * HW2];
        float2 r2 = rp[(c * NCH + 2) * HW2];
        const float Ac = A_s[c];
        float sv[2]  = { s2.x, s2.y };
        float rr0[2] = { r0.x, r0.y };
        float rr1[2] = { r1.x, r1.y };
        float rr2[2] = { r2.x, r2.y };
        #pragma unroll
        for (int j = 0; j < 2; ++j) {
            float s  = sv[j];
            float lp = fmaxf(__logf(s), LOG_CLAMP);
            float l1 = fmaxf(__logf(1.0f - s), LOG_CLAMP);
            float d0 = rr0[j] - t[0][j];
            float d1 = rr1[j] - t[1][j];
            float d2 = rr2[j] - t[2][j];
            float D  = d0 * d0 + d1 * d1 + d2 * d2;
            float U = 0.f, V = 0.f;
            #pragma unroll
            for (int s7 = 0; s7 < NS; ++s7) {
                float a = ai_s[s7][c];
                U = fmaf(mb[j][s7], a, U);
                V = fmaf(vb[j][s7], a, V);
            }
            acc += -(Ac * l1 + U * (lp - l1)) * INV_HW + 0.1f * V * D;
        }
    }

    // wave reduce then cross-wave via LDS, one atomic per block
    #pragma unroll
    for (int off = 32; off; off >>= 1) acc += __shfl_down(acc, off, 64);
    __shared__ float wsum[BLOCK / 64];
    const int wid  = tid >> 6;
    const int lane = tid & 63;
    if (lane == 0) wsum[wid] = acc;
    __syncthreads();
    if (tid == 0) {
        float a = wsum[0] + wsum[1] + wsum[2] + wsum[3];
        atomicAdd(out, a * SCALE);
    }
}

extern "C" void kernel_launch(void* const* d_in, const int* in_sizes, int n_in,
                              void* d_out, int out_size, void* d_ws, size_t ws_size,
                              hipStream_t stream) {
    const float* seg   = (const float*)d_in[0];  // (4,6,8,128,128)
    const float* masks = (const float*)d_in[1];  // (4,6,7,128,128)
    const float* rec   = (const float*)d_in[2];  // (4,6,8,3,128,128)
    const float* rtgt  = (const float*)d_in[3];  // (4,6,3,128,128)
    const float* mvis  = (const float*)d_in[4];  // (4,6,7,128,128)
    const float* ai    = (const float*)d_in[5];  // (4,6,7,8)
    float* out = (float*)d_out;

    hipMemsetAsync(out, 0, sizeof(float), stream);
    em_loss_kernel<<<BF * CHUNKS, BLOCK, 0, stream>>>(seg, masks, rec, rtgt, mvis, ai, out);
}